// Round 18
// baseline (195.604 us; speedup 1.0000x reference)
//
#include <hip/hip_runtime.h>

// CTC batch loss (keras ctc_batch_cost), B=256, T=512, C=256, U=64.
// Split-T fwd/bwd decomposition. Evidence r3-r11: five disjoint staged
// data paths all give kernel ~37-39us = 14 GB/s/CU with 1 block/CU -- a
// per-CU service cap, not latency/in-flight or issue. So: halve per-CU
// bytes + double independent blocks.
//
//   loss = -log(v0^T alpha_511), alpha_t = D_t A alpha_{t-1}
//        = -log( y^T alpha_256 ),  y = chain of (A^T D_t) over t=511..257
// Block (b,0): forward t=0..256 -> alpha_256 (129 states + esum).
// Block (b,1): backward (transpose) t=511..257 + final A^T -> y.
// K2 (256 tiny blocks): fp64 dot + log (fp32 would overflow: both vectors
// are 2^60-normalized).  512 blocks = 2/CU, 256 KB y_pred per block.
//
// Per-block structure = r10's verified scheme (4 waves, wave w stages rows
// 4w..4w+3 of each 16-row chunk via global_load_lds dwordx4; counted
// vmcnt(8) per iter, never 0 in main loop; NBUF=4 ring, 64 KB; wave 0
// gathers row[label]/row[255] via alias-opaque asm ds_read + lgkm fence
// (rule #18) and runs the recurrence). 16 chunks per half, no clamps:
// fwd t=1+16c+i in [1,256]; bwd t=496-16c+i in [256,511] (t=256 staged,
// unused). Rescale cadence t%8==0 in BOTH directions (fwd: (1+i)&7==0;
// bwd: i%8==0 since 496-16c is a multiple of 8).
// Backward lane math (lane l owns states 2l even/blank, 2l+1 odd/label;
// lane63 also state 128): (A^T u)[2l] = u_e[l]+u_o[l];
// (A^T u)[2l+1] = u_o[l] + (l==63 ? u_top : u_e[l+1]) + sk_next[l]*u_o[l+1];
// (A^T u)[128] = u_top. sk_next[l] = l<63 && label[l+1]!=label[l].
// wave_shl1 = DPP 0x130 (lane l <- l+1, lane63 -> 0), mirror of the
// verified 0x138 wave_shr1.

constexpr int B = 256, T = 512, C = 256, U = 64;
constexpr int CH = 16;   // rows per chunk
constexpr int NCH = 16;  // chunks per half
constexpr int WSH = 130; // floats per half result (64 e, 64 o, top, esum)
constexpr int WSB = 260; // floats per batch
#define EPSF 1e-7f

#define LDSA(p) ((unsigned)(size_t)(__attribute__((address_space(3))) void*)(p))

__device__ __forceinline__ float dpp_wave_shr1(float x) {
    // lane l <- lane l-1; lane 0 -> 0 (bound_ctrl). Verified r0-r11.
    return __int_as_float(__builtin_amdgcn_update_dpp(
        0, __float_as_int(x), 0x138, 0xf, 0xf, true));
}
__device__ __forceinline__ float dpp_wave_shl1(float x) {
    // lane l <- lane l+1; lane 63 -> 0 (bound_ctrl).
    return __int_as_float(__builtin_amdgcn_update_dpp(
        0, __float_as_int(x), 0x130, 0xf, 0xf, true));
}

#define DPPMAX(ctrl)                                                      \
    {                                                                     \
        float x_ = __int_as_float(__builtin_amdgcn_update_dpp(            \
            0, __float_as_int(m_), (ctrl), 0xf, 0xf, true));              \
        m_ = fmaxf(m_, x_);                                               \
    }

#define RESCALE()                                                         \
    {                                                                     \
        float m_ = fmaxf(fmaxf(a_even, a_odd), a_top);                    \
        DPPMAX(0x111) DPPMAX(0x112) DPPMAX(0x114) DPPMAX(0x118)           \
        DPPMAX(0x142) DPPMAX(0x143)                                       \
        const float mx_ = __int_as_float(                                 \
            __builtin_amdgcn_readlane(__float_as_int(m_), 63));           \
        int e_ = (__float_as_int(mx_) >> 23) & 0xff;                      \
        int k_ = 187 - e_;                                                \
        k_ = k_ > 127 ? 127 : k_;                                         \
        const float s_ = __int_as_float((k_ + 127) << 23);                \
        a_even *= s_; a_odd *= s_; a_top *= s_;                           \
        esum += k_;                                                       \
    }

// Wave stages its 4 rows (i = rbase..rbase+3) of chunk cc (row-base RT)
// into rows[cc & 3]. One dwordx4 gload_lds per row = linear 1 KB copy.
#define STAGE_W(cc, RT)                                                    \
    {                                                                      \
        float* lbase_ = &rows[(cc) & 3][0][0];                             \
        _Pragma("unroll")                                                  \
        for (int j = 0; j < 4; ++j) {                                      \
            const int i_ = rbase + j;                                      \
            const int t_ = (RT) + i_;                                      \
            const float* g_ = rowp + t_ * C + (lane << 2);                 \
            __builtin_amdgcn_global_load_lds(                              \
                (const __attribute__((address_space(1))) void*)g_,         \
                (__attribute__((address_space(3))) void*)(lbase_ + i_ * C),\
                16, 0, 0);                                                 \
        }                                                                  \
    }

#define DSR(dst, addr, OS)                                                 \
    asm volatile("ds_read_b32 %0, %1 offset:" OS                           \
                 : "=v"(dst) : "v"(addr));

// w0: 32 LDS gathers for one chunk (labels per-lane, blank broadcast).
#define GATHER(LA, BA)                                                     \
    {                                                                      \
        DSR(lab[0],  LA, "0")     DSR(lab[1],  LA, "1024")                 \
        DSR(lab[2],  LA, "2048")  DSR(lab[3],  LA, "3072")                 \
        DSR(lab[4],  LA, "4096")  DSR(lab[5],  LA, "5120")                 \
        DSR(lab[6],  LA, "6144")  DSR(lab[7],  LA, "7168")                 \
        DSR(lab[8],  LA, "8192")  DSR(lab[9],  LA, "9216")                 \
        DSR(lab[10], LA, "10240") DSR(lab[11], LA, "11264")                \
        DSR(lab[12], LA, "12288") DSR(lab[13], LA, "13312")                \
        DSR(lab[14], LA, "14336") DSR(lab[15], LA, "15360")                \
        DSR(blk[0],  BA, "0")     DSR(blk[1],  BA, "1024")                 \
        DSR(blk[2],  BA, "2048")  DSR(blk[3],  BA, "3072")                 \
        DSR(blk[4],  BA, "4096")  DSR(blk[5],  BA, "5120")                 \
        DSR(blk[6],  BA, "6144")  DSR(blk[7],  BA, "7168")                 \
        DSR(blk[8],  BA, "8192")  DSR(blk[9],  BA, "9216")                 \
        DSR(blk[10], BA, "10240") DSR(blk[11], BA, "11264")                \
        DSR(blk[12], BA, "12288") DSR(blk[13], BA, "13312")                \
        DSR(blk[14], BA, "14336") DSR(blk[15], BA, "15360")                \
    }

#define LGKM_FENCE()                                                       \
    asm volatile("s_waitcnt lgkmcnt(0)" ::: "memory");                     \
    __builtin_amdgcn_sched_barrier(0);

#define VMC(N)                                                             \
    asm volatile("s_waitcnt vmcnt(" #N ")" ::: "memory");                  \
    __builtin_amdgcn_sched_barrier(0);

// Forward step block (verified r0-r11): rescale when t%8==0 <=> (1+i)&7==0.
#define COMP_FWD()                                                         \
    {                                                                      \
        _Pragma("unroll")                                                  \
        for (int i = 0; i < CH; ++i) {                                     \
            const float pb = blk[i] + EPSF;                                \
            const float pl = lab[i] + EPSF;                                \
            const float po = dpp_wave_shr1(a_odd);                         \
            const float skp = skip_ok ? po : 0.f;                          \
            const float ne = (a_even + po) * pb;                           \
            const float no = (a_odd + a_even + skp) * pl;                  \
            const float nt = (a_top + a_odd) * pb;                         \
            a_even = ne; a_odd = no; a_top = nt;                           \
            if (((1 + i) & 7) == 0) RESCALE();                             \
        }                                                                  \
    }

// One backward (transpose) step at row i; DO_R = compile-time rescale flag.
#define BSTEP(i, DO_R)                                                     \
    {                                                                      \
        const float pb = blk[i] + EPSF;                                    \
        const float pl = lab[i] + EPSF;                                    \
        const float se = dpp_wave_shl1(a_even);                            \
        const float so = dpp_wave_shl1(a_odd);                             \
        const float fu = (lane == 63) ? a_top : se;                        \
        const float ne = (a_even + a_odd) * pb;                            \
        const float no = (a_odd + fu + (sk_next ? so : 0.f)) * pl;         \
        const float nt = a_top * pb;                                       \
        a_even = ne; a_odd = no; a_top = nt;                               \
        if (DO_R) RESCALE();                                               \
    }

// Backward chunk c=0: i=15 is the t=511 init (u = D_511 v0), then 15 steps.
#define COMP_BWD_FIRST()                                                   \
    {                                                                      \
        a_odd  = (lane == 63) ? lab[15] + EPSF : 0.f;                      \
        a_top  = blk[15] + EPSF;                                           \
        a_even = 0.f;                                                      \
        _Pragma("unroll")                                                  \
        for (int i = 14; i >= 0; --i) BSTEP(i, (i == 8) || (i == 0))       \
    }
#define COMP_BWD_MID()                                                     \
    {                                                                      \
        _Pragma("unroll")                                                  \
        for (int i = 15; i >= 0; --i) BSTEP(i, (i == 8) || (i == 0))       \
    }
// Backward chunk c=15: steps t=271..257 (i=15..1; i=0 is t=256, fwd-owned),
// then the final pure A^T (no D), leaving y in a_even/a_odd/a_top.
#define COMP_BWD_LAST()                                                    \
    {                                                                      \
        _Pragma("unroll")                                                  \
        for (int i = 15; i >= 1; --i) BSTEP(i, (i == 8))                   \
        const float se = dpp_wave_shl1(a_even);                            \
        const float so = dpp_wave_shl1(a_odd);                             \
        const float fu = (lane == 63) ? a_top : se;                        \
        const float ye = a_even + a_odd;                                   \
        const float yo = a_odd + fu + (sk_next ? so : 0.f);                \
        a_even = ye; a_odd = yo;                                           \
    }

#define DO_COMP(cc)                                                        \
    if (half) {                                                            \
        if ((cc) == 0) { COMP_BWD_FIRST() } else { COMP_BWD_MID() }        \
    } else { COMP_FWD() }

__global__ __launch_bounds__(256) void ctc_half(const int* __restrict__ y_true,
                                                const float* __restrict__ y_pred,
                                                float* __restrict__ ws) {
    __shared__ float rows[4][CH][C];  // 64 KB ring (2 blocks/CU = 128 KB)
    const int bid = blockIdx.x;
    const int b = bid >> 1, half = bid & 1;
    const int tid = threadIdx.x, lane = tid & 63, wid = tid >> 6;
    const int rbase = wid << 2;
    const float* __restrict__ rowp = y_pred + (size_t)b * (T * C);

    const int label = y_true[b * U + lane];
    const int label_prev = __shfl_up(label, 1);
    const int label_next = __shfl_down(label, 1);
    const bool skip_ok = (lane > 0) && (label != label_prev);
    const bool sk_next = (lane < 63) && (label_next != label);

    float a_even = 0.f, a_odd = 0.f, a_top = 0.f;
    int esum = 0;  // stored = true * 2^esum
    float lab[CH], blk[CH];

    if (half == 0 && wid == 0) {
        // fwd t = 0 init (linear domain; unreachable states = 0).
        const float pb = rowp[C - 1] + EPSF;
        const float pl = rowp[label] + EPSF;
        a_even = (lane == 0) ? pb : 0.f;
        a_odd  = (lane == 0) ? pl : 0.f;
    }

    const unsigned labB = LDSA(&rows[0][0][label]);
    const unsigned blkB = LDSA(&rows[0][0][C - 1]);
    const int rt0 = half ? 496 : 1;     // chunk c row-base = rt0 + rts*c
    const int rts = half ? -16 : 16;

    // Drain init/label loads so asm vmcnt bookkeeping is exact (all waves).
    asm volatile("s_waitcnt vmcnt(0)" ::: "memory");
    __builtin_amdgcn_sched_barrier(0);

    // Prologue: stage chunks 0..2 (12 loads/wave), verify own chunk-0 rows.
    STAGE_W(0, rt0)
    STAGE_W(1, rt0 + rts)
    STAGE_W(2, rt0 + 2 * rts)
    VMC(8)
    __builtin_amdgcn_s_barrier();

    // Main loop c = 0..12: gather+compute chunk c, stage chunk c+3.
    for (int c = 0; c < 13; ++c) {
        const unsigned off = (unsigned)(c & 3) << 14;
        if (wid == 0) { GATHER(labB + off, blkB + off) }
        __builtin_amdgcn_sched_barrier(0);
        STAGE_W(c + 3, rt0 + (c + 3) * rts)
        if (wid == 0) {
            LGKM_FENCE();
            DO_COMP(c)
        }
        VMC(8)
        __builtin_amdgcn_s_barrier();
    }
    // c = 13: outstanding {14,15} = 8 -> wait 4 => chunk 14 landed.
    if (wid == 0) {
        GATHER(labB + (1u << 14), blkB + (1u << 14))
        LGKM_FENCE();
        DO_COMP(13)
    }
    VMC(4)
    __builtin_amdgcn_s_barrier();
    // c = 14: wait 0 => chunk 15 landed.
    if (wid == 0) {
        GATHER(labB + (2u << 14), blkB + (2u << 14))
        LGKM_FENCE();
        DO_COMP(14)
    }
    VMC(0)
    __builtin_amdgcn_s_barrier();
    // c = 15: compute + write result (no more barriers on any wave).
    if (wid == 0) {
        GATHER(labB + (3u << 14), blkB + (3u << 14))
        LGKM_FENCE();
        if (half) { COMP_BWD_LAST() } else { COMP_FWD() }
        float* wp = ws + b * WSB + half * WSH;
        wp[lane] = a_even;
        wp[64 + lane] = a_odd;
        if (lane == 63) {
            wp[128] = a_top;
            wp[129] = (float)esum;
        }
    }
}

__global__ __launch_bounds__(64) void ctc_combine(const float* __restrict__ ws,
                                                  float* __restrict__ out) {
    const int b = blockIdx.x;
    const int l = threadIdx.x;
    const float* fp = ws + b * WSB;
    const float* bp = fp + WSH;
    double s = (double)fp[l] * (double)bp[l] +
               (double)fp[64 + l] * (double)bp[64 + l];
    if (l == 63) s += (double)fp[128] * (double)bp[128];
    for (int off = 32; off; off >>= 1) s += __shfl_xor(s, off);
    if (l == 0) {
        const float ef = fp[129], eb = bp[129];
        out[b] = (float)(-log(s) +
                         (double)(ef + eb) * 0.6931471805599453);
    }
}

extern "C" void kernel_launch(void* const* d_in, const int* in_sizes, int n_in,
                              void* d_out, int out_size, void* d_ws, size_t ws_size,
                              hipStream_t stream) {
    const int* y_true   = (const int*)d_in[0];
    const float* y_pred = (const float*)d_in[1];
    float* out = (float*)d_out;
    float* ws  = (float*)d_ws;  // needs 256*260*4 = 266 KB
    hipLaunchKernelGGL(ctc_half, dim3(2 * B), dim3(256), 0, stream,
                       y_true, y_pred, ws);
    hipLaunchKernelGGL(ctc_combine, dim3(B), dim3(64), 0, stream, ws, out);
}